// Round 1
// baseline (1627.720 us; speedup 1.0000x reference)
//
#include <hip/hip_runtime.h>
#include <math.h>

#define TSEQ   2048
#define NBATCH 4
#define NHEAD  16
#define HDIM   64
#define DMODEL 1024
#define MROWS  (NBATCH * TSEQ)   // 8192
#define ATTN_SCALE 8.0f          // sqrt(head_dim), faithful to source bug

// ---------------------------------------------------------------------------
// Fused QKV projection: Y[m,n] = sum_k X[m,k]*W[n,k] + bias[n]
// blockIdx.z selects {Q,K,V}. Output written in [B,H,T,hd] layout.
// 128x128 tile, 8x8 per thread, K-chunk 32. fp32 (no fp32 MFMA on CDNA4).
// ---------------------------------------------------------------------------
__global__ __launch_bounds__(256, 2) void qkv_gemm(
    const float* __restrict__ X,
    const float* __restrict__ Wq, const float* __restrict__ bq,
    const float* __restrict__ Wk, const float* __restrict__ bk,
    const float* __restrict__ Wv, const float* __restrict__ bv,
    float* __restrict__ Qo, float* __restrict__ Ko, float* __restrict__ Vo)
{
    const float* W; const float* bias; float* out;
    if (blockIdx.z == 0)      { W = Wq; bias = bq; out = Qo; }
    else if (blockIdx.z == 1) { W = Wk; bias = bk; out = Ko; }
    else                      { W = Wv; bias = bv; out = Vo; }

    // k-major tiles; stride 132 (16B aligned rows, 2-way-at-most store banking)
    __shared__ __align__(16) float At[32][132];
    __shared__ __align__(16) float Bt[32][132];

    const int tid = threadIdx.x;
    const int bm = blockIdx.y * 128;
    const int bn = blockIdx.x * 128;
    const int r0 = (tid >> 4) * 8;   // 8 output rows
    const int c0 = (tid & 15) * 8;   // 8 output cols

    float acc[8][8];
    #pragma unroll
    for (int i = 0; i < 8; i++)
        #pragma unroll
        for (int j = 0; j < 8; j++) acc[i][j] = 0.f;

    for (int k0 = 0; k0 < DMODEL; k0 += 32) {
        __syncthreads();
        #pragma unroll
        for (int t = 0; t < 4; t++) {
            int f   = tid + t * 256;      // 0..1023
            int row = f >> 3;             // 0..127
            int kq  = f & 7;              // float4 index within 32-k chunk
            float4 a = *(const float4*)(X + (size_t)(bm + row) * DMODEL + k0 + kq * 4);
            At[kq*4+0][row] = a.x; At[kq*4+1][row] = a.y;
            At[kq*4+2][row] = a.z; At[kq*4+3][row] = a.w;
            float4 b = *(const float4*)(W + (size_t)(bn + row) * DMODEL + k0 + kq * 4);
            Bt[kq*4+0][row] = b.x; Bt[kq*4+1][row] = b.y;
            Bt[kq*4+2][row] = b.z; Bt[kq*4+3][row] = b.w;
        }
        __syncthreads();
        #pragma unroll 8
        for (int kk = 0; kk < 32; kk++) {
            float a[8], b[8];
            *(float4*)&a[0] = *(const float4*)&At[kk][r0];
            *(float4*)&a[4] = *(const float4*)&At[kk][r0 + 4];
            *(float4*)&b[0] = *(const float4*)&Bt[kk][c0];
            *(float4*)&b[4] = *(const float4*)&Bt[kk][c0 + 4];
            #pragma unroll
            for (int i = 0; i < 8; i++)
                #pragma unroll
                for (int j = 0; j < 8; j++)
                    acc[i][j] = fmaf(a[i], b[j], acc[i][j]);
        }
    }

    // epilogue: bias + scatter into [B,H,T,hd]
    #pragma unroll
    for (int i = 0; i < 8; i++) {
        int m  = bm + r0 + i;
        int b_ = m >> 11;        // / TSEQ
        int t_ = m & 2047;
        #pragma unroll
        for (int j = 0; j < 8; j++) {
            int n = bn + c0 + j;
            int h = n >> 6, d = n & 63;
            out[(((size_t)(b_ * NHEAD + h) * TSEQ + t_) << 6) + d] = acc[i][j] + bias[n];
        }
    }
}

// ---------------------------------------------------------------------------
// Flash-style causal attention, fp32. One block per (q-tile of 64, b*h).
// LDS: Q^T[d][row], K^T[d][col] (union'd with P^T[col][row]), V[row][d].
// All compute-loop LDS reads use a wave-uniform row index -> conflict-free.
// ---------------------------------------------------------------------------
__global__ __launch_bounds__(256, 2) void attn_fwd(
    const float* __restrict__ Q,   // [BH][T][64]
    const float* __restrict__ K,
    const float* __restrict__ V,
    float* __restrict__ out)       // [B][T][1024]
{
    __shared__ __align__(16) float Qtd[64][68];  // [d][row]
    __shared__ __align__(16) float KP[64][68];   // K^T [d][col]; later P^T [col][row]
    __shared__ __align__(16) float Vt[64][68];   // [row][d]

    const int tid = threadIdx.x;
    const int qt  = blockIdx.x;    // 0..31
    const int bh  = blockIdx.y;    // 0..63
    const int b   = bh >> 4, h = bh & 15;

    const float* Qbase = Q + ((size_t)bh * TSEQ + qt * 64) * HDIM;
    #pragma unroll
    for (int t = 0; t < 4; t++) {
        int f = tid + t * 256;
        int row = f >> 4, d0 = (f & 15) * 4;
        float4 v = *(const float4*)(Qbase + row * HDIM + d0);
        Qtd[d0+0][row] = v.x; Qtd[d0+1][row] = v.y;
        Qtd[d0+2][row] = v.z; Qtd[d0+3][row] = v.w;
    }

    const int ty = tid >> 4, tx = tid & 15;   // thread owns rows ty*4+i, cols tx*4+j
    float O[4][4];
    #pragma unroll
    for (int i = 0; i < 4; i++)
        #pragma unroll
        for (int j = 0; j < 4; j++) O[i][j] = 0.f;
    float mrow[4] = {-1e30f, -1e30f, -1e30f, -1e30f};
    float lrow[4] = {0.f, 0.f, 0.f, 0.f};

    for (int kt = 0; kt <= qt; kt++) {
        __syncthreads();   // also covers initial Qtd fill
        const float* Kbase = K + ((size_t)bh * TSEQ + kt * 64) * HDIM;
        const float* Vbase = V + ((size_t)bh * TSEQ + kt * 64) * HDIM;
        #pragma unroll
        for (int t = 0; t < 4; t++) {
            int f = tid + t * 256;
            int row = f >> 4, d0 = (f & 15) * 4;
            float4 kv = *(const float4*)(Kbase + row * HDIM + d0);
            KP[d0+0][row] = kv.x; KP[d0+1][row] = kv.y;
            KP[d0+2][row] = kv.z; KP[d0+3][row] = kv.w;
            float4 vv = *(const float4*)(Vbase + row * HDIM + d0);
            *(float4*)&Vt[row][d0] = vv;
        }
        __syncthreads();

        // S = Q K^T (4x4 per thread)
        float s[4][4];
        #pragma unroll
        for (int i = 0; i < 4; i++)
            #pragma unroll
            for (int j = 0; j < 4; j++) s[i][j] = 0.f;
        #pragma unroll 8
        for (int d = 0; d < 64; d++) {
            float4 qv = *(const float4*)&Qtd[d][ty * 4];
            float4 kv = *(const float4*)&KP[d][tx * 4];
            float qa[4] = {qv.x, qv.y, qv.z, qv.w};
            float ka[4] = {kv.x, kv.y, kv.z, kv.w};
            #pragma unroll
            for (int i = 0; i < 4; i++)
                #pragma unroll
                for (int j = 0; j < 4; j++)
                    s[i][j] = fmaf(qa[i], ka[j], s[i][j]);
        }

        // scale, causal mask, online softmax
        const bool diag = (kt == qt);
        #pragma unroll
        for (int i = 0; i < 4; i++) {
            int lrowi = ty * 4 + i;
            #pragma unroll
            for (int j = 0; j < 4; j++) {
                float v = s[i][j] * ATTN_SCALE;
                if (diag && (tx * 4 + j > lrowi)) v = -1e30f;
                s[i][j] = v;
            }
            float mx = fmaxf(fmaxf(s[i][0], s[i][1]), fmaxf(s[i][2], s[i][3]));
            #pragma unroll
            for (int off = 1; off < 16; off <<= 1)
                mx = fmaxf(mx, __shfl_xor(mx, off, 64));
            float mnew  = fmaxf(mrow[i], mx);
            float alpha = __expf(mrow[i] - mnew);
            float sum = 0.f;
            #pragma unroll
            for (int j = 0; j < 4; j++) {
                s[i][j] = __expf(s[i][j] - mnew);
                sum += s[i][j];
            }
            #pragma unroll
            for (int off = 1; off < 16; off <<= 1)
                sum += __shfl_xor(sum, off, 64);
            lrow[i] = lrow[i] * alpha + sum;
            mrow[i] = mnew;
            #pragma unroll
            for (int j = 0; j < 4; j++) O[i][j] *= alpha;
        }

        __syncthreads();   // everyone done reading K^T before overwriting with P^T
        #pragma unroll
        for (int i = 0; i < 4; i++)
            #pragma unroll
            for (int j = 0; j < 4; j++)
                KP[tx * 4 + j][ty * 4 + i] = s[i][j];   // P^T[col][row]
        __syncthreads();

        // O += P V
        #pragma unroll 4
        for (int jj = 0; jj < 64; jj++) {
            float4 pv = *(const float4*)&KP[jj][ty * 4];
            float4 vv = *(const float4*)&Vt[jj][tx * 4];
            float pa[4] = {pv.x, pv.y, pv.z, pv.w};
            float va[4] = {vv.x, vv.y, vv.z, vv.w};
            #pragma unroll
            for (int i = 0; i < 4; i++)
                #pragma unroll
                for (int x = 0; x < 4; x++)
                    O[i][x] = fmaf(pa[i], va[x], O[i][x]);
        }
    }

    // epilogue: normalize, write [B,T,H*hd]
    float* obase = out + ((size_t)b * TSEQ + qt * 64) * DMODEL + h * HDIM;
    #pragma unroll
    for (int i = 0; i < 4; i++) {
        float inv = 1.0f / lrow[i];
        int row = ty * 4 + i;
        float4 r;
        r.x = O[i][0] * inv; r.y = O[i][1] * inv;
        r.z = O[i][2] * inv; r.w = O[i][3] * inv;
        *(float4*)(obase + (size_t)row * DMODEL + tx * 4) = r;
    }
}

// ---------------------------------------------------------------------------
extern "C" void kernel_launch(void* const* d_in, const int* in_sizes, int n_in,
                              void* d_out, int out_size, void* d_ws, size_t ws_size,
                              hipStream_t stream)
{
    const float* x  = (const float*)d_in[0];
    const float* Wq = (const float*)d_in[1];
    const float* bq = (const float*)d_in[2];
    const float* Wk = (const float*)d_in[3];
    const float* bk = (const float*)d_in[4];
    const float* Wv = (const float*)d_in[5];
    const float* bv = (const float*)d_in[6];

    // workspace: Q,K,V in [B,H,T,hd] fp32 — 3 * 32 MB = 96 MB
    float* Qw = (float*)d_ws;
    float* Kw = Qw + (size_t)MROWS * DMODEL;
    float* Vw = Kw + (size_t)MROWS * DMODEL;
    float* out = (float*)d_out;

    dim3 gg(DMODEL / 128, MROWS / 128, 3);
    qkv_gemm<<<gg, 256, 0, stream>>>(x, Wq, bq, Wk, bk, Wv, bv, Qw, Kw, Vw);

    dim3 ga(TSEQ / 64, NBATCH * NHEAD);
    attn_fwd<<<ga, 256, 0, stream>>>(Qw, Kw, Vw, out);
}

// Round 2
// 1017.763 us; speedup vs baseline: 1.5993x; 1.5993x over previous
//
#include <hip/hip_runtime.h>
#include <math.h>

#define TSEQ   2048
#define NBATCH 4
#define NHEAD  16
#define HDIM   64
#define DMODEL 1024
#define MROWS  (NBATCH * TSEQ)   // 8192
// fold 8 * log2(e) into Q so softmax runs in exp2 domain (v_exp_f32 native)
#define QSCALE 11.541560327111707f

typedef float f32x4  __attribute__((ext_vector_type(4)));
typedef short bf16x8 __attribute__((ext_vector_type(8)));

static __device__ __forceinline__ short f2bf(float f) {  // RNE float->bf16
    union { float f; unsigned u; } a; a.f = f;
    unsigned r = a.u + 0x7FFFu + ((a.u >> 16) & 1u);
    return (short)(r >> 16);
}
static __device__ __forceinline__ float bf2f(short s) {
    union { unsigned u; float f; } a; a.u = ((unsigned)(unsigned short)s) << 16;
    return a.f;
}

// ---------------------------------------------------------------------------
// QKV projection (fp32 compute, unchanged): epilogue now emits
//   z=0: Qhi/Qlo bf16 (value scaled by 8*log2e), z=1: Khi/Klo bf16, z=2: V bf16
// all in [B*H][T][64] layout.
// ---------------------------------------------------------------------------
__global__ __launch_bounds__(256, 2) void qkv_gemm(
    const float* __restrict__ X,
    const float* __restrict__ Wq, const float* __restrict__ bq,
    const float* __restrict__ Wk, const float* __restrict__ bk,
    const float* __restrict__ Wv, const float* __restrict__ bv,
    short* __restrict__ Qhi, short* __restrict__ Qlo,
    short* __restrict__ Khi, short* __restrict__ Klo,
    short* __restrict__ Vb)
{
    const float* W; const float* bias;
    if (blockIdx.z == 0)      { W = Wq; bias = bq; }
    else if (blockIdx.z == 1) { W = Wk; bias = bk; }
    else                      { W = Wv; bias = bv; }

    __shared__ __align__(16) float At[32][132];
    __shared__ __align__(16) float Bt[32][132];

    const int tid = threadIdx.x;
    const int bm = blockIdx.y * 128;
    const int bn = blockIdx.x * 128;
    const int r0 = (tid >> 4) * 8;
    const int c0 = (tid & 15) * 8;

    float acc[8][8];
    #pragma unroll
    for (int i = 0; i < 8; i++)
        #pragma unroll
        for (int j = 0; j < 8; j++) acc[i][j] = 0.f;

    for (int k0 = 0; k0 < DMODEL; k0 += 32) {
        __syncthreads();
        #pragma unroll
        for (int t = 0; t < 4; t++) {
            int f   = tid + t * 256;
            int row = f >> 3;
            int kq  = f & 7;
            float4 a = *(const float4*)(X + (size_t)(bm + row) * DMODEL + k0 + kq * 4);
            At[kq*4+0][row] = a.x; At[kq*4+1][row] = a.y;
            At[kq*4+2][row] = a.z; At[kq*4+3][row] = a.w;
            float4 b = *(const float4*)(W + (size_t)(bn + row) * DMODEL + k0 + kq * 4);
            Bt[kq*4+0][row] = b.x; Bt[kq*4+1][row] = b.y;
            Bt[kq*4+2][row] = b.z; Bt[kq*4+3][row] = b.w;
        }
        __syncthreads();
        #pragma unroll 8
        for (int kk = 0; kk < 32; kk++) {
            float a[8], b[8];
            *(float4*)&a[0] = *(const float4*)&At[kk][r0];
            *(float4*)&a[4] = *(const float4*)&At[kk][r0 + 4];
            *(float4*)&b[0] = *(const float4*)&Bt[kk][c0];
            *(float4*)&b[4] = *(const float4*)&Bt[kk][c0 + 4];
            #pragma unroll
            for (int i = 0; i < 8; i++)
                #pragma unroll
                for (int j = 0; j < 8; j++)
                    acc[i][j] = fmaf(a[i], b[j], acc[i][j]);
        }
    }

    // epilogue: bias (+scale for Q), bf16 split, scatter into [B,H,T,64]
    const int z = blockIdx.z;
    const float scale = (z == 0) ? QSCALE : 1.0f;
    const int n0 = bn + c0;
    const int h  = n0 >> 6;
    const int d0 = n0 & 63;

    #pragma unroll
    for (int i = 0; i < 8; i++) {
        int m  = bm + r0 + i;
        int b_ = m >> 11;
        int t_ = m & 2047;
        size_t idx = (((size_t)(b_ * NHEAD + h) * TSEQ + t_) << 6) + d0;
        if (z == 2) {
            short vs[8];
            #pragma unroll
            for (int j = 0; j < 8; j++) vs[j] = f2bf(acc[i][j] + bias[n0 + j]);
            *(float4*)(Vb + idx) = *(const float4*)vs;
        } else {
            short* Hd = (z == 0) ? Qhi : Khi;
            short* Ld = (z == 0) ? Qlo : Klo;
            short hs[8], ls[8];
            #pragma unroll
            for (int j = 0; j < 8; j++) {
                float v = (acc[i][j] + bias[n0 + j]) * scale;
                short hb = f2bf(v);
                hs[j] = hb;
                ls[j] = f2bf(v - bf2f(hb));
            }
            *(float4*)(Hd + idx) = *(const float4*)hs;
            *(float4*)(Ld + idx) = *(const float4*)ls;
        }
    }
}

// ---------------------------------------------------------------------------
// MFMA flash attention. Block = 256 thr = 4 waves; Q-tile 64 rows (16/wave);
// K/V-tiles of 64. QK^T = split-bf16 (3 MFMA, ~fp32 acc precision); PV bf16.
// LDS stride 72 bf16 everywhere -> all b128 accesses conflict-free.
// P is wave-private in LDS (no barrier for the C->A layout round trip).
// ---------------------------------------------------------------------------
__global__ __launch_bounds__(256, 4) void attn_fwd(
    const short* __restrict__ Qhi, const short* __restrict__ Qlo,
    const short* __restrict__ Khi, const short* __restrict__ Klo,
    const short* __restrict__ Vb,
    float* __restrict__ out)
{
    __shared__ __align__(16) short Kh_lds[64 * 72];
    __shared__ __align__(16) short Kl_lds[64 * 72];
    __shared__ __align__(16) short Vt_lds[64 * 72];   // V^T: [d][k]
    __shared__ __align__(16) short P_lds [64 * 72];   // [w*16+m][k], wave-private strips

    const int tid  = threadIdx.x;
    const int qt   = 31 - blockIdx.x;      // heavy blocks first
    const int bh   = blockIdx.y;
    const int b    = bh >> 4, h = bh & 15;
    const int w    = tid >> 6;
    const int lane = tid & 63;
    const int t    = lane & 15;
    const int quad = lane >> 4;

    // Q A-frags, direct from global: A[m=lane&15][k=quad*8+j], k-halves 0/1
    const size_t qrow = (size_t)bh * TSEQ + qt * 64 + w * 16 + t;
    bf16x8 qh0 = *(const bf16x8*)(Qhi + qrow * 64 + quad * 8);
    bf16x8 qh1 = *(const bf16x8*)(Qhi + qrow * 64 + 32 + quad * 8);
    bf16x8 ql0 = *(const bf16x8*)(Qlo + qrow * 64 + quad * 8);
    bf16x8 ql1 = *(const bf16x8*)(Qlo + qrow * 64 + 32 + quad * 8);

    f32x4 O[4];
    #pragma unroll
    for (int i = 0; i < 4; i++) O[i] = (f32x4){0.f, 0.f, 0.f, 0.f};
    float m_st[4] = {-1e30f, -1e30f, -1e30f, -1e30f};
    float l_st[4] = {0.f, 0.f, 0.f, 0.f};

    for (int kt = 0; kt <= qt; kt++) {
        __syncthreads();   // all waves done with previous K/V tiles
        {
            const short* Ksh = Khi + ((size_t)bh * TSEQ + kt * 64) * 64;
            const short* Ksl = Klo + ((size_t)bh * TSEQ + kt * 64) * 64;
            const short* Vs  = Vb  + ((size_t)bh * TSEQ + kt * 64) * 64;
            #pragma unroll
            for (int t2 = 0; t2 < 2; t2++) {
                int c = tid + t2 * 256;           // 0..511 chunks of 8 bf16
                {   // K: coalesced load, row-major b128 store
                    int row = c >> 3, dq = c & 7;
                    *(float4*)&Kh_lds[row * 72 + dq * 8] =
                        *(const float4*)(Ksh + row * 64 + dq * 8);
                    *(float4*)&Kl_lds[row * 72 + dq * 8] =
                        *(const float4*)(Ksl + row * 64 + dq * 8);
                }
                {   // V: transpose into Vt[d][k] (wave-uniform dq -> ~no conflicts)
                    int row = c & 63, dq = c >> 6;
                    float4 vv = *(const float4*)(Vs + row * 64 + dq * 8);
                    short vs[8]; *(float4*)vs = vv;
                    #pragma unroll
                    for (int cc = 0; cc < 8; cc++)
                        Vt_lds[(dq * 8 + cc) * 72 + row] = vs[cc];
                }
            }
        }
        __syncthreads();

        // ---- S = Q K^T via split-bf16: 4 col-tiles x 2 k-halves x 3 mfma ----
        f32x4 S[4];
        #pragma unroll
        for (int ct = 0; ct < 4; ct++) {
            S[ct] = (f32x4){0.f, 0.f, 0.f, 0.f};
            #pragma unroll
            for (int dh = 0; dh < 2; dh++) {
                bf16x8 kh = *(const bf16x8*)&Kh_lds[(ct*16 + t)*72 + dh*32 + quad*8];
                bf16x8 kl = *(const bf16x8*)&Kl_lds[(ct*16 + t)*72 + dh*32 + quad*8];
                bf16x8 qh = dh ? qh1 : qh0;
                bf16x8 ql = dh ? ql1 : ql0;
                S[ct] = __builtin_amdgcn_mfma_f32_16x16x32_bf16(ql, kh, S[ct], 0, 0, 0);
                S[ct] = __builtin_amdgcn_mfma_f32_16x16x32_bf16(qh, kl, S[ct], 0, 0, 0);
                S[ct] = __builtin_amdgcn_mfma_f32_16x16x32_bf16(qh, kh, S[ct], 0, 0, 0);
            }
        }

        // causal mask on the diagonal tile (C-layout: row=quad*4+r, col=ct*16+t)
        if (kt == qt) {
            #pragma unroll
            for (int ct = 0; ct < 4; ct++) {
                int col = ct * 16 + t;
                #pragma unroll
                for (int r = 0; r < 4; r++)
                    if (col > w * 16 + quad * 4 + r) S[ct][r] = -1e30f;
            }
        }

        // ---- online softmax (log2 domain; scale folded into Q) ----
        #pragma unroll
        for (int r = 0; r < 4; r++) {
            float mx = fmaxf(fmaxf(S[0][r], S[1][r]), fmaxf(S[2][r], S[3][r]));
            mx = fmaxf(mx, __shfl_xor(mx, 1, 64));
            mx = fmaxf(mx, __shfl_xor(mx, 2, 64));
            mx = fmaxf(mx, __shfl_xor(mx, 4, 64));
            mx = fmaxf(mx, __shfl_xor(mx, 8, 64));
            float mn = fmaxf(m_st[r], mx);
            float al = exp2f(m_st[r] - mn);
            m_st[r] = mn;
            float sum = 0.f;
            #pragma unroll
            for (int ct = 0; ct < 4; ct++) {
                float p = exp2f(S[ct][r] - mn);
                S[ct][r] = p;
                sum += p;
            }
            sum += __shfl_xor(sum, 1, 64);
            sum += __shfl_xor(sum, 2, 64);
            sum += __shfl_xor(sum, 4, 64);
            sum += __shfl_xor(sum, 8, 64);
            l_st[r] = l_st[r] * al + sum;
            #pragma unroll
            for (int ct2 = 0; ct2 < 4; ct2++) O[ct2][r] *= al;
        }

        // ---- P: C-layout -> A-layout via wave-private LDS strip ----
        #pragma unroll
        for (int ct = 0; ct < 4; ct++)
            #pragma unroll
            for (int r = 0; r < 4; r++)
                P_lds[(w * 16 + quad * 4 + r) * 72 + ct * 16 + t] = f2bf(S[ct][r]);
        // (compiler inserts lgkmcnt wait; same-wave dependency only)

        bf16x8 p0 = *(const bf16x8*)&P_lds[(w * 16 + t) * 72 + quad * 8];
        bf16x8 p1 = *(const bf16x8*)&P_lds[(w * 16 + t) * 72 + 32 + quad * 8];

        // ---- O += P V : 4 d-tiles x 2 k-halves ----
        #pragma unroll
        for (int ct2 = 0; ct2 < 4; ct2++) {
            bf16x8 v0 = *(const bf16x8*)&Vt_lds[(ct2*16 + t)*72 + quad*8];
            bf16x8 v1 = *(const bf16x8*)&Vt_lds[(ct2*16 + t)*72 + 32 + quad*8];
            O[ct2] = __builtin_amdgcn_mfma_f32_16x16x32_bf16(p0, v0, O[ct2], 0, 0, 0);
            O[ct2] = __builtin_amdgcn_mfma_f32_16x16x32_bf16(p1, v1, O[ct2], 0, 0, 0);
        }
    }

    // epilogue: normalize, write [B][T][H*64] fp32
    float inv[4];
    #pragma unroll
    for (int r = 0; r < 4; r++) inv[r] = 1.0f / l_st[r];
    float* ob = out + ((size_t)b * TSEQ + qt * 64 + w * 16 + quad * 4) * DMODEL + h * 64;
    #pragma unroll
    for (int ct2 = 0; ct2 < 4; ct2++)
        #pragma unroll
        for (int r = 0; r < 4; r++)
            ob[(size_t)r * DMODEL + ct2 * 16 + t] = O[ct2][r] * inv[r];
}

// ---------------------------------------------------------------------------
extern "C" void kernel_launch(void* const* d_in, const int* in_sizes, int n_in,
                              void* d_out, int out_size, void* d_ws, size_t ws_size,
                              hipStream_t stream)
{
    const float* x  = (const float*)d_in[0];
    const float* Wq = (const float*)d_in[1];
    const float* bq = (const float*)d_in[2];
    const float* Wk = (const float*)d_in[3];
    const float* bk = (const float*)d_in[4];
    const float* Wv = (const float*)d_in[5];
    const float* bv = (const float*)d_in[6];

    // workspace: 5 bf16 tensors [BH][T][64] = 16 MB each (80 MB total)
    const size_t TEN = (size_t)MROWS * DMODEL;   // 8M elements
    short* Qhi = (short*)d_ws;
    short* Qlo = Qhi + TEN;
    short* Khi = Qlo + TEN;
    short* Klo = Khi + TEN;
    short* Vb  = Klo + TEN;
    float* out = (float*)d_out;

    dim3 gg(DMODEL / 128, MROWS / 128, 3);
    qkv_gemm<<<gg, 256, 0, stream>>>(x, Wq, bq, Wk, bk, Wv, bv,
                                     Qhi, Qlo, Khi, Klo, Vb);

    dim3 ga(TSEQ / 64, NBATCH * NHEAD);
    attn_fwd<<<ga, 256, 0, stream>>>(Qhi, Qlo, Khi, Klo, Vb, out);
}

// Round 3
// 571.978 us; speedup vs baseline: 2.8458x; 1.7794x over previous
//
#include <hip/hip_runtime.h>
#include <math.h>

#define TSEQ   2048
#define NBATCH 4
#define NHEAD  16
#define HDIM   64
#define DMODEL 1024
#define MROWS  (NBATCH * TSEQ)   // 8192
// fold 8 * log2(e) into Q so softmax runs in exp2 domain (v_exp_f32 native)
#define QSCALE 11.541560327111707f

typedef float f32x4  __attribute__((ext_vector_type(4)));
typedef short bf16x8 __attribute__((ext_vector_type(8)));

static __device__ __forceinline__ short f2bf(float f) {  // RNE float->bf16
    union { float f; unsigned u; } a; a.f = f;
    unsigned r = a.u + 0x7FFFu + ((a.u >> 16) & 1u);
    return (short)(r >> 16);
}
static __device__ __forceinline__ float bf2f(short s) {
    union { unsigned u; float f; } a; a.u = ((unsigned)(unsigned short)s) << 16;
    return a.f;
}

// async global->LDS, 16B per lane; LDS dest = wave-uniform base + lane*16
static __device__ __forceinline__ void async_copy16(short* lds, const short* g) {
    __builtin_amdgcn_global_load_lds(
        (const __attribute__((address_space(1))) void*)g,
        (__attribute__((address_space(3))) void*)lds, 16, 0, 0);
}

// ---------------------------------------------------------------------------
// fp32 -> (hi, lo) bf16 split, vectorized float4.
// ---------------------------------------------------------------------------
__global__ __launch_bounds__(256) void split32(
    const float* __restrict__ src, short* __restrict__ hi,
    short* __restrict__ lo, int n4)
{
    int i = blockIdx.x * 256 + threadIdx.x;
    if (i >= n4) return;
    float4 v = ((const float4*)src)[i];
    float f[4] = {v.x, v.y, v.z, v.w};
    short h[4], l[4];
    #pragma unroll
    for (int c = 0; c < 4; c++) {
        h[c] = f2bf(f[c]);
        l[c] = f2bf(f[c] - bf2f(h[c]));
    }
    *(float2*)(hi + (size_t)i * 4) = *(const float2*)h;
    *(float2*)(lo + (size_t)i * 4) = *(const float2*)l;
}

// ---------------------------------------------------------------------------
// Split-bf16 MFMA GEMM: Y[m,n] = sum_k X[m,k] W[n,k] + bias[n]  (~fp32 acc)
// 128x128 tile, 4 waves 2x2 (64x64 each), BK=32, 16B global_load_lds staging.
// LDS rows are 64B (no pad; required by global_load_lds); read-side bank
// conflicts broken by XOR-swizzling the four 16B k-chunks per row:
//   slot = kq ^ ((row>>1)&3)   (applied to SOURCE addr at staging + at ds_read)
// Epilogue: bias (+QSCALE for z=0), bf16 hi/lo split, scatter to [B,H,T,64].
// ---------------------------------------------------------------------------
__global__ __launch_bounds__(256, 2) void qkv_gemm_mfma(
    const short* __restrict__ Xhi, const short* __restrict__ Xlo,
    const short* __restrict__ Wh3, const short* __restrict__ Wl3,  // [3][N][K]
    const float* __restrict__ bq, const float* __restrict__ bk,
    const float* __restrict__ bv,
    short* __restrict__ Qhi, short* __restrict__ Qlo,
    short* __restrict__ Khi, short* __restrict__ Klo,
    short* __restrict__ Vb)
{
    const int z = blockIdx.z;
    const short* Wh = Wh3 + (size_t)z * DMODEL * DMODEL;
    const short* Wl = Wl3 + (size_t)z * DMODEL * DMODEL;
    const float* bias = (z == 0) ? bq : (z == 1) ? bk : bv;

    __shared__ __align__(16) short Ah[128 * 32];
    __shared__ __align__(16) short Al[128 * 32];
    __shared__ __align__(16) short Bh[128 * 32];
    __shared__ __align__(16) short Bl[128 * 32];

    const int tid  = threadIdx.x;
    const int w    = tid >> 6;
    const int lane = tid & 63;
    const int t    = lane & 15;
    const int quad = lane >> 4;
    const int wm   = w >> 1, wn = w & 1;
    const int bm   = blockIdx.y * 128;
    const int bn   = blockIdx.x * 128;

    // staging lane geometry: 16 rows x 64B per instruction
    const int r_local = lane >> 2;                       // 0..15
    const int kq      = (lane & 3) ^ ((r_local >> 1) & 3); // swizzled source chunk
    const int row0    = w * 32 + r_local;                // i=0 row; i=1 adds 16

    // read-side swizzle (row>>1)&3 == (t>>1)&3 for all tiles used below
    const int slotq = (quad ^ ((t >> 1) & 3)) * 8;

    f32x4 acc[4][4];
    #pragma unroll
    for (int i = 0; i < 4; i++)
        #pragma unroll
        for (int j = 0; j < 4; j++) acc[i][j] = (f32x4){0.f, 0.f, 0.f, 0.f};

    for (int k0 = 0; k0 < DMODEL; k0 += 32) {
        __syncthreads();
        #pragma unroll
        for (int i = 0; i < 2; i++) {
            int row = row0 + i * 16;
            size_t ga = (size_t)(bm + row) * DMODEL + k0 + kq * 8;
            size_t gb = (size_t)(bn + row) * DMODEL + k0 + kq * 8;
            int ldst = (w * 32 + i * 16) * 32;
            async_copy16(&Ah[ldst], Xhi + ga);
            async_copy16(&Al[ldst], Xlo + ga);
            async_copy16(&Bh[ldst], Wh + gb);
            async_copy16(&Bl[ldst], Wl + gb);
        }
        __syncthreads();

        bf16x8 ah[4], al[4], bh[4], bl[4];
        #pragma unroll
        for (int mt = 0; mt < 4; mt++) {
            int off = (wm * 64 + mt * 16 + t) * 32 + slotq;
            ah[mt] = *(const bf16x8*)&Ah[off];
            al[mt] = *(const bf16x8*)&Al[off];
        }
        #pragma unroll
        for (int nt = 0; nt < 4; nt++) {
            int off = (wn * 64 + nt * 16 + t) * 32 + slotq;
            bh[nt] = *(const bf16x8*)&Bh[off];
            bl[nt] = *(const bf16x8*)&Bl[off];
        }
        #pragma unroll
        for (int mt = 0; mt < 4; mt++)
            #pragma unroll
            for (int nt = 0; nt < 4; nt++) {
                acc[mt][nt] = __builtin_amdgcn_mfma_f32_16x16x32_bf16(
                    al[mt], bh[nt], acc[mt][nt], 0, 0, 0);
                acc[mt][nt] = __builtin_amdgcn_mfma_f32_16x16x32_bf16(
                    ah[mt], bl[nt], acc[mt][nt], 0, 0, 0);
                acc[mt][nt] = __builtin_amdgcn_mfma_f32_16x16x32_bf16(
                    ah[mt], bh[nt], acc[mt][nt], 0, 0, 0);
            }
    }

    // epilogue: C-layout col = t, row = quad*4 + r
    const float scale = (z == 0) ? QSCALE : 1.0f;
    float bvs[4];
    #pragma unroll
    for (int nt = 0; nt < 4; nt++)
        bvs[nt] = bias[bn + wn * 64 + nt * 16 + t];

    #pragma unroll
    for (int mt = 0; mt < 4; mt++) {
        #pragma unroll
        for (int r = 0; r < 4; r++) {
            int m  = bm + wm * 64 + mt * 16 + quad * 4 + r;
            int b_ = m >> 11;
            int t_ = m & 2047;
            #pragma unroll
            for (int nt = 0; nt < 4; nt++) {
                int d = nt * 16 + t;                       // 0..63
                int h = ((bn + wn * 64) >> 6) + 0;         // head of this 64-col strip
                size_t idx = (((size_t)(b_ * NHEAD + h) * TSEQ + t_) << 6) + d;
                float v = (acc[mt][nt][r] + bvs[nt]) * scale;
                if (z == 2) {
                    Vb[idx] = f2bf(v);
                } else {
                    short hb = f2bf(v);
                    short lb = f2bf(v - bf2f(hb));
                    if (z == 0) { Qhi[idx] = hb; Qlo[idx] = lb; }
                    else        { Khi[idx] = hb; Klo[idx] = lb; }
                }
            }
        }
    }
}

// ---------------------------------------------------------------------------
// MFMA flash attention (unchanged from R2). Block = 4 waves; Q-tile 64 rows;
// split-bf16 QK^T (3 MFMA), bf16 PV. LDS stride 72 -> conflict-free b128.
// ---------------------------------------------------------------------------
__global__ __launch_bounds__(256, 4) void attn_fwd(
    const short* __restrict__ Qhi, const short* __restrict__ Qlo,
    const short* __restrict__ Khi, const short* __restrict__ Klo,
    const short* __restrict__ Vb,
    float* __restrict__ out)
{
    __shared__ __align__(16) short Kh_lds[64 * 72];
    __shared__ __align__(16) short Kl_lds[64 * 72];
    __shared__ __align__(16) short Vt_lds[64 * 72];   // V^T: [d][k]
    __shared__ __align__(16) short P_lds [64 * 72];   // wave-private strips

    const int tid  = threadIdx.x;
    const int qt   = 31 - blockIdx.x;      // heavy blocks first
    const int bh   = blockIdx.y;
    const int b    = bh >> 4, h = bh & 15;
    const int w    = tid >> 6;
    const int lane = tid & 63;
    const int t    = lane & 15;
    const int quad = lane >> 4;

    const size_t qrow = (size_t)bh * TSEQ + qt * 64 + w * 16 + t;
    bf16x8 qh0 = *(const bf16x8*)(Qhi + qrow * 64 + quad * 8);
    bf16x8 qh1 = *(const bf16x8*)(Qhi + qrow * 64 + 32 + quad * 8);
    bf16x8 ql0 = *(const bf16x8*)(Qlo + qrow * 64 + quad * 8);
    bf16x8 ql1 = *(const bf16x8*)(Qlo + qrow * 64 + 32 + quad * 8);

    f32x4 O[4];
    #pragma unroll
    for (int i = 0; i < 4; i++) O[i] = (f32x4){0.f, 0.f, 0.f, 0.f};
    float m_st[4] = {-1e30f, -1e30f, -1e30f, -1e30f};
    float l_st[4] = {0.f, 0.f, 0.f, 0.f};

    for (int kt = 0; kt <= qt; kt++) {
        __syncthreads();
        {
            const short* Ksh = Khi + ((size_t)bh * TSEQ + kt * 64) * 64;
            const short* Ksl = Klo + ((size_t)bh * TSEQ + kt * 64) * 64;
            const short* Vs  = Vb  + ((size_t)bh * TSEQ + kt * 64) * 64;
            #pragma unroll
            for (int t2 = 0; t2 < 2; t2++) {
                int c = tid + t2 * 256;
                {
                    int row = c >> 3, dq = c & 7;
                    *(float4*)&Kh_lds[row * 72 + dq * 8] =
                        *(const float4*)(Ksh + row * 64 + dq * 8);
                    *(float4*)&Kl_lds[row * 72 + dq * 8] =
                        *(const float4*)(Ksl + row * 64 + dq * 8);
                }
                {
                    int row = c & 63, dq = c >> 6;
                    float4 vv = *(const float4*)(Vs + row * 64 + dq * 8);
                    short vs[8]; *(float4*)vs = vv;
                    #pragma unroll
                    for (int cc = 0; cc < 8; cc++)
                        Vt_lds[(dq * 8 + cc) * 72 + row] = vs[cc];
                }
            }
        }
        __syncthreads();

        f32x4 S[4];
        #pragma unroll
        for (int ct = 0; ct < 4; ct++) {
            S[ct] = (f32x4){0.f, 0.f, 0.f, 0.f};
            #pragma unroll
            for (int dh = 0; dh < 2; dh++) {
                bf16x8 kh = *(const bf16x8*)&Kh_lds[(ct*16 + t)*72 + dh*32 + quad*8];
                bf16x8 kl = *(const bf16x8*)&Kl_lds[(ct*16 + t)*72 + dh*32 + quad*8];
                bf16x8 qh = dh ? qh1 : qh0;
                bf16x8 ql = dh ? ql1 : ql0;
                S[ct] = __builtin_amdgcn_mfma_f32_16x16x32_bf16(ql, kh, S[ct], 0, 0, 0);
                S[ct] = __builtin_amdgcn_mfma_f32_16x16x32_bf16(qh, kl, S[ct], 0, 0, 0);
                S[ct] = __builtin_amdgcn_mfma_f32_16x16x32_bf16(qh, kh, S[ct], 0, 0, 0);
            }
        }

        if (kt == qt) {
            #pragma unroll
            for (int ct = 0; ct < 4; ct++) {
                int col = ct * 16 + t;
                #pragma unroll
                for (int r = 0; r < 4; r++)
                    if (col > w * 16 + quad * 4 + r) S[ct][r] = -1e30f;
            }
        }

        #pragma unroll
        for (int r = 0; r < 4; r++) {
            float mx = fmaxf(fmaxf(S[0][r], S[1][r]), fmaxf(S[2][r], S[3][r]));
            mx = fmaxf(mx, __shfl_xor(mx, 1, 64));
            mx = fmaxf(mx, __shfl_xor(mx, 2, 64));
            mx = fmaxf(mx, __shfl_xor(mx, 4, 64));
            mx = fmaxf(mx, __shfl_xor(mx, 8, 64));
            float mn = fmaxf(m_st[r], mx);
            float al = exp2f(m_st[r] - mn);
            m_st[r] = mn;
            float sum = 0.f;
            #pragma unroll
            for (int ct = 0; ct < 4; ct++) {
                float p = exp2f(S[ct][r] - mn);
                S[ct][r] = p;
                sum += p;
            }
            sum += __shfl_xor(sum, 1, 64);
            sum += __shfl_xor(sum, 2, 64);
            sum += __shfl_xor(sum, 4, 64);
            sum += __shfl_xor(sum, 8, 64);
            l_st[r] = l_st[r] * al + sum;
            #pragma unroll
            for (int ct2 = 0; ct2 < 4; ct2++) O[ct2][r] *= al;
        }

        #pragma unroll
        for (int ct = 0; ct < 4; ct++)
            #pragma unroll
            for (int r = 0; r < 4; r++)
                P_lds[(w * 16 + quad * 4 + r) * 72 + ct * 16 + t] = f2bf(S[ct][r]);

        bf16x8 p0 = *(const bf16x8*)&P_lds[(w * 16 + t) * 72 + quad * 8];
        bf16x8 p1 = *(const bf16x8*)&P_lds[(w * 16 + t) * 72 + 32 + quad * 8];

        #pragma unroll
        for (int ct2 = 0; ct2 < 4; ct2++) {
            bf16x8 v0 = *(const bf16x8*)&Vt_lds[(ct2*16 + t)*72 + quad*8];
            bf16x8 v1 = *(const bf16x8*)&Vt_lds[(ct2*16 + t)*72 + 32 + quad*8];
            O[ct2] = __builtin_amdgcn_mfma_f32_16x16x32_bf16(p0, v0, O[ct2], 0, 0, 0);
            O[ct2] = __builtin_amdgcn_mfma_f32_16x16x32_bf16(p1, v1, O[ct2], 0, 0, 0);
        }
    }

    float inv[4];
    #pragma unroll
    for (int r = 0; r < 4; r++) inv[r] = 1.0f / l_st[r];
    float* ob = out + ((size_t)b * TSEQ + qt * 64 + w * 16 + quad * 4) * DMODEL + h * 64;
    #pragma unroll
    for (int ct2 = 0; ct2 < 4; ct2++)
        #pragma unroll
        for (int r = 0; r < 4; r++)
            ob[(size_t)r * DMODEL + ct2 * 16 + t] = O[ct2][r] * inv[r];
}

// ---------------------------------------------------------------------------
extern "C" void kernel_launch(void* const* d_in, const int* in_sizes, int n_in,
                              void* d_out, int out_size, void* d_ws, size_t ws_size,
                              hipStream_t stream)
{
    const float* x  = (const float*)d_in[0];
    const float* Wq = (const float*)d_in[1];
    const float* bq = (const float*)d_in[2];
    const float* Wk = (const float*)d_in[3];
    const float* bk = (const float*)d_in[4];
    const float* Wv = (const float*)d_in[5];
    const float* bv = (const float*)d_in[6];

    // workspace (shorts): Xhi/Xlo 8M ea, Whi/Wlo 3M ea, Q/K hi+lo + V 8M ea
    const size_t TEN = (size_t)MROWS * DMODEL;   // 8M
    const size_t WEN = (size_t)DMODEL * DMODEL;  // 1M
    short* Xhi = (short*)d_ws;
    short* Xlo = Xhi + TEN;
    short* Whi = Xlo + TEN;
    short* Wlo = Whi + 3 * WEN;
    short* Qhi = Wlo + 3 * WEN;
    short* Qlo = Qhi + TEN;
    short* Khi = Qlo + TEN;
    short* Klo = Khi + TEN;
    short* Vb  = Klo + TEN;
    float* out = (float*)d_out;

    split32<<<(int)(TEN / 4 / 256), 256, 0, stream>>>(x, Xhi, Xlo, (int)(TEN / 4));
    split32<<<(int)(WEN / 4 / 256), 256, 0, stream>>>(Wq, Whi, Wlo, (int)(WEN / 4));
    split32<<<(int)(WEN / 4 / 256), 256, 0, stream>>>(Wk, Whi + WEN, Wlo + WEN, (int)(WEN / 4));
    split32<<<(int)(WEN / 4 / 256), 256, 0, stream>>>(Wv, Whi + 2 * WEN, Wlo + 2 * WEN, (int)(WEN / 4));

    dim3 gg(DMODEL / 128, MROWS / 128, 3);
    qkv_gemm_mfma<<<gg, 256, 0, stream>>>(Xhi, Xlo, Whi, Wlo, bq, bk, bv,
                                          Qhi, Qlo, Khi, Klo, Vb);

    dim3 ga(TSEQ / 64, NBATCH * NHEAD);
    attn_fwd<<<ga, 256, 0, stream>>>(Qhi, Qlo, Khi, Klo, Vb, out);
}